// Round 8
// baseline (502.642 us; speedup 1.0000x reference)
//
#include <hip/hip_runtime.h>
#include <hip/hip_bf16.h>
#include <stdint.h>

// Problem constants (S=8, B=16, N=500, D=128, K=50, L=6)
#define G_   128
#define N_   500
#define NP_  512          // padded N (stride)
#define D_   128
#define K_   50
#define L_   6
#define NW_  16           // adjacency words per row
#define ROWT 125

typedef __attribute__((ext_vector_type(8))) short bf16x8;
typedef __attribute__((ext_vector_type(4))) float f32x4;

#define ADJ_BYTES  ((size_t)G_ * N_ * NW_ * 4)      //  4,096,000
#define EBUF_BYTES ((size_t)G_ * 32 * 1024 * 4)     // 16,777,216
#define ECNT_BYTES ((size_t)G_ * 32 * 4)            //     16,384
#define HB_BYTES   ((size_t)G_ * NP_ * D_ * 2)      // 16,777,216 each
#define WT_BYTES   ((size_t)L_ * D_ * D_ * 2)       //    196,608

// layer_kernel dynamic LDS (69,664 B -> 2 blocks/CU)
#define L_B0   0          // buf0: hTA 16K + gate 16K
#define L_B1   32768      // buf1: hTA 16K + gate 16K
#define L_ECNT 69632      // u32[8] bucket counts
#define LDS_TOTAL 69664

__device__ __forceinline__ float silu_f(float z) {
    return z * __builtin_amdgcn_rcpf(1.0f + __expf(-z));
}
__device__ __forceinline__ unsigned short f2bf(float f) {
    uint32_t u = __float_as_uint(f);
    u += 0x7fffu + ((u >> 16) & 1u);
    return (unsigned short)(u >> 16);
}
__device__ __forceinline__ float bf2f(unsigned short s) {
    return __uint_as_float(((uint32_t)s) << 16);
}

// ---------------------------------------------------------------------------
// K0: kNN via radix-2 binary search of the 50th-smallest SQUARED distance
// (round-6 version, 87 us measured; radix-4 regressed: SALU-bound).
// d^2 < 2.0 -> bit30==0, search bits 29..0. One wave per row.
// ---------------------------------------------------------------------------
__global__ __launch_bounds__(256) void knn_kernel(const float* __restrict__ x,
                                                  uint32_t* __restrict__ adj) {
    int g    = blockIdx.x / ROWT;
    int tile = blockIdx.x % ROWT;
    int wv   = threadIdx.x >> 6;
    int lane = threadIdx.x & 63;
    int i    = tile * 4 + wv;

    __shared__ float2 c[N_];
    for (int t = threadIdx.x; t < N_; t += 256)
        c[t] = ((const float2*)x)[(size_t)g * N_ + t];
    __syncthreads();

    float2 ci = c[i];
    uint32_t kb[8];
#pragma unroll
    for (int r = 0; r < 8; ++r) {
        int j = lane + r * 64;
        float dv;
        if (j < N_ && j != i) {
            float dx = ci.x - c[j].x, dy = ci.y - c[j].y;
            dv = dx * dx + dy * dy;          // squared distance: same order
        } else {
            dv = 3.0e38f;
        }
        kb[r] = __float_as_uint(dv);
    }

    uint32_t prefix = 0;
    for (int bit = 29; bit >= 0; --bit) {
        uint32_t cand = prefix | (1u << bit);
        int cnt = 0;
#pragma unroll
        for (int r = 0; r < 8; ++r)
            cnt += __popcll(__ballot(kb[r] < cand));
        if (cnt < K_) prefix = cand;
    }

    unsigned long long sel[8];
    int cntless = 0;
#pragma unroll
    for (int r = 0; r < 8; ++r) {
        sel[r] = __ballot(kb[r] < prefix);
        cntless += __popcll(sel[r]);
    }
    int rem = K_ - cntless;
    unsigned long long tb[8];
    int tietot = 0;
#pragma unroll
    for (int r = 0; r < 8; ++r) {
        tb[r] = __ballot(kb[r] == prefix);
        tietot += __popcll(tb[r]);
    }
    if (tietot == rem) {
#pragma unroll
        for (int r = 0; r < 8; ++r) sel[r] |= tb[r];
    } else {
#pragma unroll
        for (int r = 0; r < 8; ++r) {
            unsigned long long t2 = tb[r];
            while (rem > 0 && t2) {
                unsigned long long lb = t2 & (~t2 + 1ull);
                sel[r] |= lb;
                t2 ^= lb;
                --rem;
            }
        }
    }

    uint32_t* arow = adj + ((size_t)g * N_ + i) * NW_;
#pragma unroll
    for (int r = 0; r < 8; ++r) {
        if (lane == 2 * r)     arow[2 * r]     = (uint32_t)sel[r];
        if (lane == 2 * r + 1) arow[2 * r + 1] = (uint32_t)(sel[r] >> 32);
    }
}

// ---------------------------------------------------------------------------
// K0b: symmetrize bitmask in LDS and emit tile-bucketed edge lists:
// bucket (it,jt) holds packed u32 records (il:7 | jl:6 | distbits>>11 :19).
// LDS-atomic slot counters -> fully parallel emission. One block per graph.
// ---------------------------------------------------------------------------
__global__ __launch_bounds__(512) void ebuild_kernel(const float* __restrict__ x,
                                                     const uint32_t* __restrict__ adj,
                                                     uint32_t* __restrict__ ebuf,
                                                     uint32_t* __restrict__ ecnt) {
    int g = blockIdx.x, tid = threadIdx.x;
    __shared__ uint32_t am[N_][NW_];   // 32,000 B (directed adjacency)
    __shared__ float2   c[N_];         //  4,000 B
    __shared__ uint32_t bcnt[32];

    for (int t = tid; t < N_; t += 512)
        c[t] = ((const float2*)x)[(size_t)g * N_ + t];
    const uint32_t* ag = adj + (size_t)g * N_ * NW_;
    for (int t = tid; t < N_ * NW_; t += 512)
        ((uint32_t*)am)[t] = ag[t];
    if (tid < 32) bcnt[tid] = 0;
    __syncthreads();

    uint32_t buf[16];
    int cnt = 0;
    for (int idx = tid; idx < N_ * NW_; idx += 512) {
        int ii = idx >> 4, w = idx & 15;
        uint32_t v = am[ii][w];
        int jb = w << 5;
        int jmax = (jb + 32 <= N_) ? 32 : (N_ - jb);
        uint32_t wi = (uint32_t)ii >> 5, bi = ii & 31;
        for (int b = 0; b < jmax; ++b)
            v |= ((am[jb + b][wi] >> bi) & 1u) << b;
        buf[cnt++] = v;
    }
    __syncthreads();

    uint32_t* eg = ebuf + ((size_t)g << 15);   // g * 32 * 1024
    cnt = 0;
    for (int idx = tid; idx < N_ * NW_; idx += 512) {
        int ii = idx >> 4, w = idx & 15;
        uint32_t v = buf[cnt++];
        if (!v) continue;
        float2 ci = c[ii];
        int il = ii & 127;
        int bb = (ii >> 7) << 3;
        while (v) {
            int b = __ffs(v) - 1;
            v &= v - 1;
            int j = (w << 5) + b;
            int bucket = bb + (j >> 6);
            uint32_t slot = atomicAdd(&bcnt[bucket], 1u);
            float dx = ci.x - c[j].x, dy = ci.y - c[j].y;
            float dd = sqrtf(dx * dx + dy * dy + 1e-12f);
            uint32_t rec = ((uint32_t)il << 25) | ((uint32_t)(j & 63) << 19)
                         | (__float_as_uint(dd) >> 11);
            if (slot < 1024u)
                eg[(bucket << 10) + slot] = rec;
        }
    }
    __syncthreads();
    if (tid < 32) ecnt[(g << 5) + tid] = bcnt[tid] > 1024u ? 1024u : bcnt[tid];
}

// ---------------------------------------------------------------------------
// K0c: transpose weights to bf16: WT[l][dout][din] = bf16(W[l][din][dout])
// ---------------------------------------------------------------------------
__global__ __launch_bounds__(256) void wprep_kernel(const float* __restrict__ Ws,
                                                    const float* __restrict__ Wm,
                                                    unsigned short* __restrict__ WsT,
                                                    unsigned short* __restrict__ WmT) {
    int idx = blockIdx.x * 256 + threadIdx.x;
    int half = idx >= L_ * D_ * D_;
    int r = half ? idx - L_ * D_ * D_ : idx;
    int l = r >> 14, rr = r & 16383, dout = rr >> 7, din = rr & 127;
    const float* W = half ? Wm : Ws;
    unsigned short* O = half ? WmT : WsT;
    O[r] = f2bf(W[(size_t)l * 16384 + din * 128 + dout]);
}

// ---------------------------------------------------------------------------
// K1: h0 = silu(coords @ Wn + bn), written bf16 as h[i][d] AND hT[d][i]
// ---------------------------------------------------------------------------
__global__ __launch_bounds__(256) void enc_kernel(const float* __restrict__ x,
                                                  const float* __restrict__ Wn,
                                                  const float* __restrict__ bn,
                                                  unsigned short* __restrict__ h,
                                                  unsigned short* __restrict__ hT) {
    int g = blockIdx.x, tid = threadIdx.x;
    __shared__ float2 c[N_];
    for (int t = tid; t < N_; t += 256)
        c[t] = ((const float2*)x)[(size_t)g * N_ + t];
    __syncthreads();
    for (int o = tid; o < N_ * 16; o += 256) {
        int i = o >> 4, d0 = (o & 15) * 8;
        float2 ci = c[i];
        unsigned short u[8];
#pragma unroll
        for (int e = 0; e < 8; ++e) {
            int d = d0 + e;
            u[e] = f2bf(silu_f(ci.x * Wn[d] + ci.y * Wn[D_ + d] + bn[d]));
        }
        *(uint4*)&h[((size_t)g * NP_ + i) * D_ + d0] = *(uint4*)u;
    }
    for (int o = tid; o < D_ * 64; o += 256) {
        int d = o >> 6, io = o & 63;
        float w0 = Wn[d], w1 = Wn[D_ + d], b = bn[d];
        unsigned short u[8];
#pragma unroll
        for (int e = 0; e < 8; ++e) {
            int i = io * 8 + e;
            unsigned short val = 0;
            if (i < N_) {
                float2 ci = c[i];
                val = f2bf(silu_f(ci.x * w0 + ci.y * w1 + b));
            }
            u[e] = val;
        }
        *(uint4*)&hT[((size_t)g * D_ + d) * NP_ + io * 8] = *(uint4*)u;
    }
}

// ---------------------------------------------------------------------------
// K2: fused layer. Phase 1: mT = hT @ gateT, 8 j-tiles of 64, double-buffered
// with ASYNC-SPLIT staging: issue tile jt+1 global loads BEFORE MFMA(jt),
// LDS-write + sparse-scatter AFTER the post-MFMA barrier (latency hides under
// MFMA). Single reused accumulator (peak ~90 VGPR, no spill at the 128 cap).
// Phase 2: acc = WmT@m^T then += WsT@h^T. Epilogue via LDS -> uint4 stores.
// Grid G*4, XCD-bijective swizzle. 69.7 KB LDS -> 2 blocks/CU.
// ---------------------------------------------------------------------------
__global__ __launch_bounds__(512, 4) void layer_kernel(
    const uint32_t* __restrict__ ebuf,
    const uint32_t* __restrict__ ecnt,
    const unsigned short* __restrict__ hin,    // [G][NP_][D_]
    const unsigned short* __restrict__ hinT,   // [G][D_][NP_]
    unsigned short* __restrict__ hout,
    unsigned short* __restrict__ houtT,
    const unsigned short* __restrict__ WsT,    // [L][dout][din] bf16
    const unsigned short* __restrict__ WmT,
    const float* __restrict__ bL,
    const float* __restrict__ we,
    const float* __restrict__ be, int l)
{
    int bid = (blockIdx.x & 7) * 64 + (blockIdx.x >> 3);   // XCD-bijective
    int g  = bid >> 2;
    int it = bid & 3;
    int i0 = it * 128;
    int tid = threadIdx.x;
    int lane = tid & 63, wv = tid >> 6;
    int wrow = wv >> 2, wcol = wv & 3;   // wave tile: 64 d-rows x 32 i-cols

    extern __shared__ char lds[];
    uint32_t* ecnt_s = (uint32_t*)(lds + L_ECNT);
    char* tileI = lds;                   // epilogue [128 i][272 B]
    char* tileT = lds + 34816;           // epilogue [128 d][272 B]

    if (tid < 8) ecnt_s[tid] = ecnt[(g << 5) + (it << 3) + tid];

    float wel = we[l], bel = be[l];
    const unsigned short* hTg = hinT + (size_t)g * D_ * NP_;
    const uint32_t* ebg = ebuf + ((size_t)g << 15) + ((size_t)it << 13);

    int d_st  = tid >> 3, jo_st = tid & 7;          // staging coords (hTA)
    size_t hoff0 = (size_t)d_st * NP_ + jo_st * 8;
    size_t hoff1 = (size_t)(d_st + 64) * NP_ + jo_st * 8;
    int hbyt0 = (d_st << 7) + (jo_st << 4); hbyt0 ^= (d_st & 7) << 4;
    int hbyt1 = ((d_st + 64) << 7) + (jo_st << 4); hbyt1 ^= (d_st & 7) << 4;

    auto zerogate = [&](char* buf) {
        char* gb = buf + 16384;
        const uint4 z4 = make_uint4(0u, 0u, 0u, 0u);
        *(uint4*)(gb + tid * 16)         = z4;
        *(uint4*)(gb + (tid + 512) * 16) = z4;
    };
    // issue global loads for tile jt (no waits)
    auto loadtile = [&](int jt, uint4* hv, uint32_t& ra, uint32_t& rb) {
        int j0t = jt * 64;
        hv[0] = *(const uint4*)&hTg[hoff0 + j0t];
        hv[1] = *(const uint4*)&hTg[hoff1 + j0t];
        const uint32_t* eb = ebg + (jt << 10);
        ra = eb[tid];
        rb = eb[tid + 512];
    };
    // LDS-write staged tile (reg dependency supplies the vmcnt wait)
    auto writetile = [&](char* buf, int jt, const uint4* hv, uint32_t ra, uint32_t rb) {
        char* gateB = buf + 16384;
        *(uint4*)(buf + hbyt0) = hv[0];
        *(uint4*)(buf + hbyt1) = hv[1];
        int n = (int)ecnt_s[jt];
#pragma unroll
        for (int q = 0; q < 2; ++q) {
            uint32_t rec = q ? rb : ra;
            int e = tid + q * 512;
            if (e < n) {
                int il = rec >> 25;
                int jl = (rec >> 19) & 63;
                float dist = __uint_as_float((rec & 0x7FFFFu) << 11);
                float z = wel * dist + bel;
                float s = z * __builtin_amdgcn_rcpf(1.0f + __expf(-z));
                int byt = (il << 7) + (jl << 1);
                byt ^= (il & 7) << 4;
                *(unsigned short*)(gateB + byt) = f2bf(s);
            }
        }
    };

    f32x4 acc[4][2];
#pragma unroll
    for (int a_ = 0; a_ < 4; ++a_)
#pragma unroll
        for (int b_ = 0; b_ < 2; ++b_)
            acc[a_][b_] = (f32x4){0.f, 0.f, 0.f, 0.f};

    // ---- phase 1 prologue ----
    zerogate(lds + L_B0);
    zerogate(lds + L_B1);
    {
        uint4 hv0[2]; uint32_t ra0, rb0;
        loadtile(0, hv0, ra0, rb0);
        __syncthreads();              // zeros + ecnt_s visible
        writetile(lds + L_B0, 0, hv0, ra0, rb0);
    }
    __syncthreads();                  // buf0 ready

    // ---- phase 1 main loop: MFMA(cur) hides tile jt+1 load latency ----
#pragma unroll
    for (int jt = 0; jt < 8; ++jt) {
        char* cur = lds + ((jt & 1) ? L_B1 : L_B0);
        char* nxt = lds + ((jt & 1) ? L_B0 : L_B1);
        uint4 hvn[2]; uint32_t ra, rb;
        if (jt < 7) loadtile(jt + 1, hvn, ra, rb);
        char* hTA = cur, *gateB = cur + 16384;
#pragma unroll
        for (int kk = 0; kk < 64; kk += 32) {
            int kbyte = (kk + ((lane >> 4) << 3)) << 1;
            bf16x8 af[4], bfr[2];
#pragma unroll
            for (int fr = 0; fr < 4; ++fr) {
                int d = wrow * 64 + fr * 16 + (lane & 15);
                int byt = (d << 7) + kbyte; byt ^= (d & 7) << 4;
                af[fr] = *(const bf16x8*)(hTA + byt);
            }
#pragma unroll
            for (int fc = 0; fc < 2; ++fc) {
                int i = wcol * 32 + fc * 16 + (lane & 15);
                int byt = (i << 7) + kbyte; byt ^= (i & 7) << 4;
                bfr[fc] = *(const bf16x8*)(gateB + byt);
            }
#pragma unroll
            for (int fr = 0; fr < 4; ++fr)
#pragma unroll
                for (int fc = 0; fc < 2; ++fc)
                    acc[fr][fc] = __builtin_amdgcn_mfma_f32_16x16x32_bf16(
                        af[fr], bfr[fc], acc[fr][fc], 0, 0, 0);
        }
        __syncthreads();              // A: cur reads done by all waves
        if (jt < 6) zerogate(cur);    // prep cur for scatter at jt+1
        if (jt < 7) writetile(nxt, jt + 1, hvn, ra, rb);
        __syncthreads();              // B: nxt ready / zeros visible
    }

    // ---- phase 2 pass A: acc = WmT @ m^T  (acc reused after m-flush) ----
    char* Bt = lds + L_B1;
    char* At = lds + L_B0;
#pragma unroll
    for (int fr = 0; fr < 4; ++fr)
#pragma unroll
        for (int fc = 0; fc < 2; ++fc) {
            int dbase = wrow * 64 + fr * 16 + ((lane >> 4) << 2);
            int ib    = wcol * 32 + fc * 16 + (lane & 15);
            f32x4 v = acc[fr][fc];
            uint32_t p0 = (uint32_t)f2bf(v[0]) | ((uint32_t)f2bf(v[1]) << 16);
            uint32_t p1 = (uint32_t)f2bf(v[2]) | ((uint32_t)f2bf(v[3]) << 16);
            int byt = (ib << 8) + (dbase << 1); byt ^= (ib & 7) << 4;
            *(uint32_t*)(Bt + byt)     = p0;
            *(uint32_t*)(Bt + byt + 4) = p1;
        }
    const unsigned short* wmp = WmT + (size_t)l * D_ * D_;
#pragma unroll
    for (int p = 0; p < 4; ++p) {
        int o = tid + p * 512;
        int dout = o >> 4, ko = o & 15;
        uint4 v = *(const uint4*)&wmp[dout * 128 + ko * 8];
        int byt = (dout << 8) + (ko << 4); byt ^= (dout & 7) << 4;
        *(uint4*)(At + byt) = v;
    }
#pragma unroll
    for (int a_ = 0; a_ < 4; ++a_)
#pragma unroll
        for (int b_ = 0; b_ < 2; ++b_)
            acc[a_][b_] = (f32x4){0.f, 0.f, 0.f, 0.f};
    __syncthreads();

    auto gemm128 = [&]() {
#pragma unroll
        for (int kk = 0; kk < 128; kk += 32) {
            int kbyte = (kk + ((lane >> 4) << 3)) << 1;
            bf16x8 af[4], bfr[2];
#pragma unroll
            for (int fr = 0; fr < 4; ++fr) {
                int d = wrow * 64 + fr * 16 + (lane & 15);
                int byt = (d << 8) + kbyte; byt ^= (d & 7) << 4;
                af[fr] = *(const bf16x8*)(At + byt);
            }
#pragma unroll
            for (int fc = 0; fc < 2; ++fc) {
                int i = wcol * 32 + fc * 16 + (lane & 15);
                int byt = (i << 8) + kbyte; byt ^= (i & 7) << 4;
                bfr[fc] = *(const bf16x8*)(Bt + byt);
            }
#pragma unroll
            for (int fr = 0; fr < 4; ++fr)
#pragma unroll
                for (int fc = 0; fc < 2; ++fc)
                    acc[fr][fc] = __builtin_amdgcn_mfma_f32_16x16x32_bf16(
                        af[fr], bfr[fc], acc[fr][fc], 0, 0, 0);
        }
    };
    gemm128();
    __syncthreads();

    // ---- phase 2 pass B: acc += WsT @ h^T ----
    const unsigned short* hg = hin + (size_t)g * NP_ * D_;
#pragma unroll
    for (int p = 0; p < 4; ++p) {
        int o = tid + p * 512;
        int il = o >> 4, ko = o & 15;
        int gi = i0 + il;
        uint4 v = make_uint4(0u, 0u, 0u, 0u);
        if (gi < N_) v = *(const uint4*)&hg[(size_t)gi * D_ + ko * 8];
        int byt = (il << 8) + (ko << 4); byt ^= (il & 7) << 4;
        *(uint4*)(Bt + byt) = v;
    }
    const unsigned short* wsp = WsT + (size_t)l * D_ * D_;
#pragma unroll
    for (int p = 0; p < 4; ++p) {
        int o = tid + p * 512;
        int dout = o >> 4, ko = o & 15;
        uint4 v = *(const uint4*)&wsp[dout * 128 + ko * 8];
        int byt = (dout << 8) + (ko << 4); byt ^= (dout & 7) << 4;
        *(uint4*)(At + byt) = v;
    }
    __syncthreads();
    gemm128();

    // ---- epilogue: bias + silu -> LDS tiles -> coalesced uint4 stores ----
    __syncthreads();   // all phase-2 LDS reads done before overwrite
    const float* blp = bL + (size_t)l * D_;
#pragma unroll
    for (int fr = 0; fr < 4; ++fr)
#pragma unroll
        for (int fc = 0; fc < 2; ++fc) {
            int dbase = wrow * 64 + fr * 16 + ((lane >> 4) << 2);
            int ib = wcol * 32 + fc * 16 + (lane & 15);
            int gi = i0 + ib;
            f32x4 v = acc[fr][fc];
            float4 bias = *(const float4*)&blp[dbase];
            float o0 = silu_f(v[0] + bias.x);
            float o1 = silu_f(v[1] + bias.y);
            float o2 = silu_f(v[2] + bias.z);
            float o3 = silu_f(v[3] + bias.w);
            if (gi >= N_) { o0 = 0.f; o1 = 0.f; o2 = 0.f; o3 = 0.f; }
            unsigned short b0 = f2bf(o0), b1 = f2bf(o1);
            unsigned short b2 = f2bf(o2), b3 = f2bf(o3);
            char* pI = tileI + ib * 272 + dbase * 2;
            *(uint32_t*)pI       = (uint32_t)b0 | ((uint32_t)b1 << 16);
            *(uint32_t*)(pI + 4) = (uint32_t)b2 | ((uint32_t)b3 << 16);
            *(unsigned short*)(tileT + (dbase    ) * 272 + ib * 2) = b0;
            *(unsigned short*)(tileT + (dbase + 1) * 272 + ib * 2) = b1;
            *(unsigned short*)(tileT + (dbase + 2) * 272 + ib * 2) = b2;
            *(unsigned short*)(tileT + (dbase + 3) * 272 + ib * 2) = b3;
        }
    __syncthreads();
    unsigned short* hgO  = hout  + (size_t)g * NP_ * D_;
    unsigned short* hgOT = houtT + (size_t)g * D_ * NP_;
#pragma unroll
    for (int p = 0; p < 4; ++p) {
        int o = tid + p * 512;        // 0..2047
        int r = o >> 4, seg = o & 15;
        uint4 vI = *(const uint4*)(tileI + r * 272 + seg * 16);
        *(uint4*)&hgO[(size_t)(i0 + r) * D_ + seg * 8] = vI;
        uint4 vT = *(const uint4*)(tileT + r * 272 + seg * 16);
        *(uint4*)&hgOT[(size_t)r * NP_ + i0 + seg * 8] = vT;
    }
}

// ---------------------------------------------------------------------------
// K4: global mean pool + output projection (f32 accumulation from bf16 h)
// ---------------------------------------------------------------------------
__global__ __launch_bounds__(256) void pool_kernel(const unsigned short* __restrict__ h,
                                                   const float* __restrict__ Wo,
                                                   float* __restrict__ out) {
    int g = blockIdx.x, tid = threadIdx.x;
    const unsigned short* hg = h + (size_t)g * NP_ * D_;
    float a8[8];
#pragma unroll
    for (int e = 0; e < 8; ++e) a8[e] = 0.f;
    int d0 = (tid & 15) * 8;
    for (int i = tid >> 4; i < N_; i += 16) {
        uint4 v = *(const uint4*)&hg[(size_t)i * D_ + d0];
        const unsigned short* pu = (const unsigned short*)&v;
#pragma unroll
        for (int e = 0; e < 8; ++e) a8[e] += bf2f(pu[e]);
    }
    __shared__ float red[16][D_];
#pragma unroll
    for (int e = 0; e < 8; ++e) red[tid >> 4][d0 + e] = a8[e];
    __syncthreads();
    __shared__ float pooled[D_];
    if (tid < D_) {
        float s = 0.f;
#pragma unroll
        for (int grp = 0; grp < 16; ++grp) s += red[grp][tid];
        pooled[tid] = s * (1.0f / (float)N_);
    }
    __syncthreads();
    if (tid < D_) {
        float accv = 0.f;
        for (int k = 0; k < D_; ++k) accv += pooled[k] * Wo[(size_t)k * D_ + tid];
        out[(size_t)g * D_ + tid] = accv;
    }
}

// ---------------------------------------------------------------------------
extern "C" void kernel_launch(void* const* d_in, const int* in_sizes, int n_in,
                              void* d_out, int out_size, void* d_ws, size_t ws_size,
                              hipStream_t stream) {
    (void)in_sizes; (void)n_in; (void)out_size; (void)ws_size;
    const float* x  = (const float*)d_in[0];
    const float* Wn = (const float*)d_in[1];
    const float* bn = (const float*)d_in[2];
    const float* Ws = (const float*)d_in[3];
    const float* Wm = (const float*)d_in[4];
    const float* bL = (const float*)d_in[5];
    const float* we = (const float*)d_in[6];
    const float* be = (const float*)d_in[7];
    const float* Wo = (const float*)d_in[8];
    float* out = (float*)d_out;

    char* w = (char*)d_ws;
    uint32_t*       adj  = (uint32_t*)w;        w += ADJ_BYTES;
    uint32_t*       ebuf = (uint32_t*)w;        w += EBUF_BYTES;
    uint32_t*       ecnt = (uint32_t*)w;        w += ECNT_BYTES;
    unsigned short* hA   = (unsigned short*)w;  w += HB_BYTES;
    unsigned short* hAT  = (unsigned short*)w;  w += HB_BYTES;
    unsigned short* hB   = (unsigned short*)w;  w += HB_BYTES;
    unsigned short* hBT  = (unsigned short*)w;  w += HB_BYTES;
    unsigned short* WsT  = (unsigned short*)w;  w += WT_BYTES;
    unsigned short* WmT  = (unsigned short*)w;  w += WT_BYTES;

    hipFuncSetAttribute((const void*)layer_kernel,
                        hipFuncAttributeMaxDynamicSharedMemorySize, LDS_TOTAL);

    knn_kernel<<<G_ * ROWT, 256, 0, stream>>>(x, adj);
    ebuild_kernel<<<G_, 512, 0, stream>>>(x, adj, ebuf, ecnt);
    wprep_kernel<<<(2 * L_ * D_ * D_) / 256, 256, 0, stream>>>(Ws, Wm, WsT, WmT);
    enc_kernel<<<G_, 256, 0, stream>>>(x, Wn, bn, hA, hAT);

    for (int l = 0; l < L_; ++l) {
        const unsigned short* hi  = (l & 1) ? hB  : hA;
        const unsigned short* hiT = (l & 1) ? hBT : hAT;
        unsigned short* ho  = (l & 1) ? hA  : hB;
        unsigned short* hoT = (l & 1) ? hAT : hBT;
        layer_kernel<<<G_ * 4, 512, LDS_TOTAL, stream>>>(ebuf, ecnt, hi, hiT, ho, hoT,
                                                         WsT, WmT, bL, we, be, l);
    }

    pool_kernel<<<G_, 256, 0, stream>>>(hA, Wo, out);
}

// Round 9
// 419.708 us; speedup vs baseline: 1.1976x; 1.1976x over previous
//
#include <hip/hip_runtime.h>
#include <hip/hip_bf16.h>
#include <stdint.h>

// Problem constants (S=8, B=16, N=500, D=128, K=50, L=6)
#define G_   128
#define N_   500
#define NP_  512          // padded N (stride)
#define D_   128
#define K_   50
#define L_   6
#define NW_  16           // adjacency words per row
#define ROWT 125
#define BCAP 2048         // edge-bucket capacity (mean ~1600, ~7 sigma margin)

typedef __attribute__((ext_vector_type(8))) short bf16x8;
typedef __attribute__((ext_vector_type(4))) float f32x4;

#define ADJ_BYTES  ((size_t)G_ * N_ * NW_ * 4)      //  4,096,000
#define EBUF_BYTES ((size_t)G_ * 32 * BCAP * 4)     // 33,554,432
#define ECNT_BYTES ((size_t)G_ * 32 * 4)            //     16,384
#define HB_BYTES   ((size_t)G_ * NP_ * D_ * 2)      // 16,777,216 each
#define WT_BYTES   ((size_t)L_ * D_ * D_ * 2)       //    196,608

// layer_kernel dynamic LDS (69,664 B -> 2 blocks/CU)
#define L_B0   0          // buf0: hTA 16K + gate 16K
#define L_B1   32768      // buf1: hTA 16K + gate 16K
#define L_ECNT 69632      // u32[8] bucket counts
#define LDS_TOTAL 69664

__device__ __forceinline__ float silu_f(float z) {
    return z * __builtin_amdgcn_rcpf(1.0f + __expf(-z));
}
__device__ __forceinline__ unsigned short f2bf(float f) {
    uint32_t u = __float_as_uint(f);
    u += 0x7fffu + ((u >> 16) & 1u);
    return (unsigned short)(u >> 16);
}
__device__ __forceinline__ float bf2f(unsigned short s) {
    return __uint_as_float(((uint32_t)s) << 16);
}

// ---------------------------------------------------------------------------
// K0: kNN via radix-2 binary search of the 50th-smallest SQUARED distance,
// with EARLY EXIT: if count{d2 < cand} == 50 exactly, the set is unique
// (no boundary ties possible) -> select immediately. One wave per row.
// ---------------------------------------------------------------------------
__global__ __launch_bounds__(256) void knn_kernel(const float* __restrict__ x,
                                                  uint32_t* __restrict__ adj) {
    int g    = blockIdx.x / ROWT;
    int tile = blockIdx.x % ROWT;
    int wv   = threadIdx.x >> 6;
    int lane = threadIdx.x & 63;
    int i    = tile * 4 + wv;

    __shared__ float2 c[N_];
    for (int t = threadIdx.x; t < N_; t += 256)
        c[t] = ((const float2*)x)[(size_t)g * N_ + t];
    __syncthreads();

    float2 ci = c[i];
    uint32_t kb[8];
#pragma unroll
    for (int r = 0; r < 8; ++r) {
        int j = lane + r * 64;
        float dv;
        if (j < N_ && j != i) {
            float dx = ci.x - c[j].x, dy = ci.y - c[j].y;
            dv = dx * dx + dy * dy;          // squared distance: same order
        } else {
            dv = 3.0e38f;
        }
        kb[r] = __float_as_uint(dv);
    }

    uint32_t prefix = 0;
    int exact = 0;
    for (int bit = 29; bit >= 0; --bit) {
        uint32_t cand = prefix | (1u << bit);
        int cnt = 0;
#pragma unroll
        for (int r = 0; r < 8; ++r)
            cnt += __popcll(__ballot(kb[r] < cand));
        if (cnt == K_) { prefix = cand; exact = 1; break; }
        if (cnt < K_) prefix = cand;
    }

    unsigned long long sel[8];
    if (exact) {
#pragma unroll
        for (int r = 0; r < 8; ++r)
            sel[r] = __ballot(kb[r] < prefix);
    } else {
        int cntless = 0;
#pragma unroll
        for (int r = 0; r < 8; ++r) {
            sel[r] = __ballot(kb[r] < prefix);
            cntless += __popcll(sel[r]);
        }
        int rem = K_ - cntless;
        unsigned long long tb[8];
        int tietot = 0;
#pragma unroll
        for (int r = 0; r < 8; ++r) {
            tb[r] = __ballot(kb[r] == prefix);
            tietot += __popcll(tb[r]);
        }
        if (tietot == rem) {
#pragma unroll
            for (int r = 0; r < 8; ++r) sel[r] |= tb[r];
        } else {
#pragma unroll
            for (int r = 0; r < 8; ++r) {
                unsigned long long t2 = tb[r];
                while (rem > 0 && t2) {
                    unsigned long long lb = t2 & (~t2 + 1ull);
                    sel[r] |= lb;
                    t2 ^= lb;
                    --rem;
                }
            }
        }
    }

    uint32_t* arow = adj + ((size_t)g * N_ + i) * NW_;
#pragma unroll
    for (int r = 0; r < 8; ++r) {
        if (lane == 2 * r)     arow[2 * r]     = (uint32_t)sel[r];
        if (lane == 2 * r + 1) arow[2 * r + 1] = (uint32_t)(sel[r] >> 32);
    }
}

// ---------------------------------------------------------------------------
// K0b: DIRECTED edge walk -> dual-record emission (forward + mirror).
// No symmetrization: gate scatter is idempotent, so mutual edges producing
// duplicate records are benign. Bucket (it,jt) record: (il:7|jl:6|dist>>11:19).
// One block per graph; LDS-atomic slot counters; 50 bits/row walk only.
// ---------------------------------------------------------------------------
__global__ __launch_bounds__(512) void ebuild_kernel(const float* __restrict__ x,
                                                     const uint32_t* __restrict__ adj,
                                                     uint32_t* __restrict__ ebuf,
                                                     uint32_t* __restrict__ ecnt) {
    int g = blockIdx.x, tid = threadIdx.x;
    __shared__ uint32_t am[N_][NW_];   // 32,000 B (directed adjacency)
    __shared__ float2   c[N_];         //  4,000 B
    __shared__ uint32_t bcnt[32];

    for (int t = tid; t < N_; t += 512)
        c[t] = ((const float2*)x)[(size_t)g * N_ + t];
    const uint32_t* ag = adj + (size_t)g * N_ * NW_;
    for (int t = tid; t < N_ * NW_; t += 512)
        ((uint32_t*)am)[t] = ag[t];
    if (tid < 32) bcnt[tid] = 0;
    __syncthreads();

    uint32_t* eg = ebuf + ((size_t)g << 16);   // g * 32 * BCAP
    for (int idx = tid; idx < N_ * NW_; idx += 512) {
        int ii = idx >> 4, w = idx & 15;
        uint32_t v = am[ii][w];
        if (!v) continue;
        float2 ci = c[ii];
        while (v) {
            int b = __ffs(v) - 1;
            v &= v - 1;
            int j = (w << 5) + b;
            float dx = ci.x - c[j].x, dy = ci.y - c[j].y;
            float dd = sqrtf(dx * dx + dy * dy + 1e-12f);
            uint32_t dbits = __float_as_uint(dd) >> 11;
            // forward record: row ii, col j
            int bf = ((ii >> 7) << 3) + (j >> 6);
            uint32_t rf = ((uint32_t)(ii & 127) << 25) | ((uint32_t)(j & 63) << 19) | dbits;
            uint32_t sf = atomicAdd(&bcnt[bf], 1u);
            if (sf < (uint32_t)BCAP) eg[(bf << 11) + sf] = rf;
            // mirror record: row j, col ii
            int bm = ((j >> 7) << 3) + (ii >> 6);
            uint32_t rm = ((uint32_t)(j & 127) << 25) | ((uint32_t)(ii & 63) << 19) | dbits;
            uint32_t sm = atomicAdd(&bcnt[bm], 1u);
            if (sm < (uint32_t)BCAP) eg[(bm << 11) + sm] = rm;
        }
    }
    __syncthreads();
    if (tid < 32) ecnt[(g << 5) + tid] = bcnt[tid] > (uint32_t)BCAP ? (uint32_t)BCAP : bcnt[tid];
}

// ---------------------------------------------------------------------------
// K0c: transpose weights to bf16: WT[l][dout][din] = bf16(W[l][din][dout])
// ---------------------------------------------------------------------------
__global__ __launch_bounds__(256) void wprep_kernel(const float* __restrict__ Ws,
                                                    const float* __restrict__ Wm,
                                                    unsigned short* __restrict__ WsT,
                                                    unsigned short* __restrict__ WmT) {
    int idx = blockIdx.x * 256 + threadIdx.x;
    int half = idx >= L_ * D_ * D_;
    int r = half ? idx - L_ * D_ * D_ : idx;
    int l = r >> 14, rr = r & 16383, dout = rr >> 7, din = rr & 127;
    const float* W = half ? Wm : Ws;
    unsigned short* O = half ? WmT : WsT;
    O[r] = f2bf(W[(size_t)l * 16384 + din * 128 + dout]);
}

// ---------------------------------------------------------------------------
// K1: h0 = silu(coords @ Wn + bn), written bf16 as h[i][d] AND hT[d][i]
// ---------------------------------------------------------------------------
__global__ __launch_bounds__(256) void enc_kernel(const float* __restrict__ x,
                                                  const float* __restrict__ Wn,
                                                  const float* __restrict__ bn,
                                                  unsigned short* __restrict__ h,
                                                  unsigned short* __restrict__ hT) {
    int g = blockIdx.x, tid = threadIdx.x;
    __shared__ float2 c[N_];
    for (int t = tid; t < N_; t += 256)
        c[t] = ((const float2*)x)[(size_t)g * N_ + t];
    __syncthreads();
    for (int o = tid; o < N_ * 16; o += 256) {
        int i = o >> 4, d0 = (o & 15) * 8;
        float2 ci = c[i];
        unsigned short u[8];
#pragma unroll
        for (int e = 0; e < 8; ++e) {
            int d = d0 + e;
            u[e] = f2bf(silu_f(ci.x * Wn[d] + ci.y * Wn[D_ + d] + bn[d]));
        }
        *(uint4*)&h[((size_t)g * NP_ + i) * D_ + d0] = *(uint4*)u;
    }
    for (int o = tid; o < D_ * 64; o += 256) {
        int d = o >> 6, io = o & 63;
        float w0 = Wn[d], w1 = Wn[D_ + d], b = bn[d];
        unsigned short u[8];
#pragma unroll
        for (int e = 0; e < 8; ++e) {
            int i = io * 8 + e;
            unsigned short val = 0;
            if (i < N_) {
                float2 ci = c[i];
                val = f2bf(silu_f(ci.x * w0 + ci.y * w1 + b));
            }
            u[e] = val;
        }
        *(uint4*)&hT[((size_t)g * D_ + d) * NP_ + io * 8] = *(uint4*)u;
    }
}

// ---------------------------------------------------------------------------
// K2: fused layer. Phase 1: mT = hT @ gateT, 8 j-tiles of 64, double-buffered
// with async-split staging (loads issued before MFMA, written after barrier).
// Buckets now hold up to BCAP=2048 records (4 per thread). Phase 2:
// acc = WmT@m^T then += WsT@h^T. Epilogue via LDS -> coalesced uint4 stores.
// Grid G*4, XCD-bijective swizzle. 69.7 KB LDS -> 2 blocks/CU.
// ---------------------------------------------------------------------------
__global__ __launch_bounds__(512, 4) void layer_kernel(
    const uint32_t* __restrict__ ebuf,
    const uint32_t* __restrict__ ecnt,
    const unsigned short* __restrict__ hin,    // [G][NP_][D_]
    const unsigned short* __restrict__ hinT,   // [G][D_][NP_]
    unsigned short* __restrict__ hout,
    unsigned short* __restrict__ houtT,
    const unsigned short* __restrict__ WsT,    // [L][dout][din] bf16
    const unsigned short* __restrict__ WmT,
    const float* __restrict__ bL,
    const float* __restrict__ we,
    const float* __restrict__ be, int l)
{
    int bid = (blockIdx.x & 7) * 64 + (blockIdx.x >> 3);   // XCD-bijective
    int g  = bid >> 2;
    int it = bid & 3;
    int i0 = it * 128;
    int tid = threadIdx.x;
    int lane = tid & 63, wv = tid >> 6;
    int wrow = wv >> 2, wcol = wv & 3;   // wave tile: 64 d-rows x 32 i-cols

    extern __shared__ char lds[];
    uint32_t* ecnt_s = (uint32_t*)(lds + L_ECNT);
    char* tileI = lds;                   // epilogue [128 i][272 B]
    char* tileT = lds + 34816;           // epilogue [128 d][272 B]

    if (tid < 8) ecnt_s[tid] = ecnt[(g << 5) + (it << 3) + tid];

    float wel = we[l], bel = be[l];
    const unsigned short* hTg = hinT + (size_t)g * D_ * NP_;
    const uint32_t* ebg = ebuf + ((size_t)g << 16) + ((size_t)it << 14);

    int d_st  = tid >> 3, jo_st = tid & 7;          // staging coords (hTA)
    size_t hoff0 = (size_t)d_st * NP_ + jo_st * 8;
    size_t hoff1 = (size_t)(d_st + 64) * NP_ + jo_st * 8;
    int hbyt0 = (d_st << 7) + (jo_st << 4); hbyt0 ^= (d_st & 7) << 4;
    int hbyt1 = ((d_st + 64) << 7) + (jo_st << 4); hbyt1 ^= (d_st & 7) << 4;

    auto zerogate = [&](char* buf) {
        char* gb = buf + 16384;
        const uint4 z4 = make_uint4(0u, 0u, 0u, 0u);
        *(uint4*)(gb + tid * 16)         = z4;
        *(uint4*)(gb + (tid + 512) * 16) = z4;
    };
    // issue global loads for tile jt (no waits)
    auto loadtile = [&](int jt, uint4* hv, uint32_t* ra) {
        int j0t = jt * 64;
        hv[0] = *(const uint4*)&hTg[hoff0 + j0t];
        hv[1] = *(const uint4*)&hTg[hoff1 + j0t];
        const uint32_t* eb = ebg + (jt << 11);
#pragma unroll
        for (int q = 0; q < 4; ++q) ra[q] = eb[tid + q * 512];
    };
    // LDS-write staged tile (reg dependency supplies the vmcnt wait)
    auto writetile = [&](char* buf, int jt, const uint4* hv, const uint32_t* ra) {
        char* gateB = buf + 16384;
        *(uint4*)(buf + hbyt0) = hv[0];
        *(uint4*)(buf + hbyt1) = hv[1];
        int n = (int)ecnt_s[jt];
#pragma unroll
        for (int q = 0; q < 4; ++q) {
            uint32_t rec = ra[q];
            int e = tid + q * 512;
            if (e < n) {
                int il = rec >> 25;
                int jl = (rec >> 19) & 63;
                float dist = __uint_as_float((rec & 0x7FFFFu) << 11);
                float z = wel * dist + bel;
                float s = z * __builtin_amdgcn_rcpf(1.0f + __expf(-z));
                int byt = (il << 7) + (jl << 1);
                byt ^= (il & 7) << 4;
                *(unsigned short*)(gateB + byt) = f2bf(s);
            }
        }
    };

    f32x4 acc[4][2];
#pragma unroll
    for (int a_ = 0; a_ < 4; ++a_)
#pragma unroll
        for (int b_ = 0; b_ < 2; ++b_)
            acc[a_][b_] = (f32x4){0.f, 0.f, 0.f, 0.f};

    // ---- phase 1 prologue ----
    zerogate(lds + L_B0);
    zerogate(lds + L_B1);
    {
        uint4 hv0[2]; uint32_t ra0[4];
        loadtile(0, hv0, ra0);
        __syncthreads();              // zeros + ecnt_s visible
        writetile(lds + L_B0, 0, hv0, ra0);
    }
    __syncthreads();                  // buf0 ready

    // ---- phase 1 main loop: MFMA(cur) hides tile jt+1 load latency ----
#pragma unroll
    for (int jt = 0; jt < 8; ++jt) {
        char* cur = lds + ((jt & 1) ? L_B1 : L_B0);
        char* nxt = lds + ((jt & 1) ? L_B0 : L_B1);
        uint4 hvn[2]; uint32_t ra[4];
        if (jt < 7) loadtile(jt + 1, hvn, ra);
        char* hTA = cur, *gateB = cur + 16384;
#pragma unroll
        for (int kk = 0; kk < 64; kk += 32) {
            int kbyte = (kk + ((lane >> 4) << 3)) << 1;
            bf16x8 af[4], bfr[2];
#pragma unroll
            for (int fr = 0; fr < 4; ++fr) {
                int d = wrow * 64 + fr * 16 + (lane & 15);
                int byt = (d << 7) + kbyte; byt ^= (d & 7) << 4;
                af[fr] = *(const bf16x8*)(hTA + byt);
            }
#pragma unroll
            for (int fc = 0; fc < 2; ++fc) {
                int i = wcol * 32 + fc * 16 + (lane & 15);
                int byt = (i << 7) + kbyte; byt ^= (i & 7) << 4;
                bfr[fc] = *(const bf16x8*)(gateB + byt);
            }
#pragma unroll
            for (int fr = 0; fr < 4; ++fr)
#pragma unroll
                for (int fc = 0; fc < 2; ++fc)
                    acc[fr][fc] = __builtin_amdgcn_mfma_f32_16x16x32_bf16(
                        af[fr], bfr[fc], acc[fr][fc], 0, 0, 0);
        }
        __syncthreads();              // A: cur reads done by all waves
        if (jt < 6) zerogate(cur);    // prep cur for scatter at jt+1
        if (jt < 7) writetile(nxt, jt + 1, hvn, ra);
        __syncthreads();              // B: nxt ready / zeros visible
    }

    // ---- phase 2 pass A: acc = WmT @ m^T  (acc reused after m-flush) ----
    char* Bt = lds + L_B1;
    char* At = lds + L_B0;
#pragma unroll
    for (int fr = 0; fr < 4; ++fr)
#pragma unroll
        for (int fc = 0; fc < 2; ++fc) {
            int dbase = wrow * 64 + fr * 16 + ((lane >> 4) << 2);
            int ib    = wcol * 32 + fc * 16 + (lane & 15);
            f32x4 v = acc[fr][fc];
            uint32_t p0 = (uint32_t)f2bf(v[0]) | ((uint32_t)f2bf(v[1]) << 16);
            uint32_t p1 = (uint32_t)f2bf(v[2]) | ((uint32_t)f2bf(v[3]) << 16);
            int byt = (ib << 8) + (dbase << 1); byt ^= (ib & 7) << 4;
            *(uint32_t*)(Bt + byt)     = p0;
            *(uint32_t*)(Bt + byt + 4) = p1;
        }
    const unsigned short* wmp = WmT + (size_t)l * D_ * D_;
#pragma unroll
    for (int p = 0; p < 4; ++p) {
        int o = tid + p * 512;
        int dout = o >> 4, ko = o & 15;
        uint4 v = *(const uint4*)&wmp[dout * 128 + ko * 8];
        int byt = (dout << 8) + (ko << 4); byt ^= (dout & 7) << 4;
        *(uint4*)(At + byt) = v;
    }
#pragma unroll
    for (int a_ = 0; a_ < 4; ++a_)
#pragma unroll
        for (int b_ = 0; b_ < 2; ++b_)
            acc[a_][b_] = (f32x4){0.f, 0.f, 0.f, 0.f};
    __syncthreads();

    auto gemm128 = [&]() {
#pragma unroll
        for (int kk = 0; kk < 128; kk += 32) {
            int kbyte = (kk + ((lane >> 4) << 3)) << 1;
            bf16x8 af[4], bfr[2];
#pragma unroll
            for (int fr = 0; fr < 4; ++fr) {
                int d = wrow * 64 + fr * 16 + (lane & 15);
                int byt = (d << 8) + kbyte; byt ^= (d & 7) << 4;
                af[fr] = *(const bf16x8*)(At + byt);
            }
#pragma unroll
            for (int fc = 0; fc < 2; ++fc) {
                int i = wcol * 32 + fc * 16 + (lane & 15);
                int byt = (i << 8) + kbyte; byt ^= (i & 7) << 4;
                bfr[fc] = *(const bf16x8*)(Bt + byt);
            }
#pragma unroll
            for (int fr = 0; fr < 4; ++fr)
#pragma unroll
                for (int fc = 0; fc < 2; ++fc)
                    acc[fr][fc] = __builtin_amdgcn_mfma_f32_16x16x32_bf16(
                        af[fr], bfr[fc], acc[fr][fc], 0, 0, 0);
        }
    };
    gemm128();
    __syncthreads();

    // ---- phase 2 pass B: acc += WsT @ h^T ----
    const unsigned short* hg = hin + (size_t)g * NP_ * D_;
#pragma unroll
    for (int p = 0; p < 4; ++p) {
        int o = tid + p * 512;
        int il = o >> 4, ko = o & 15;
        int gi = i0 + il;
        uint4 v = make_uint4(0u, 0u, 0u, 0u);
        if (gi < N_) v = *(const uint4*)&hg[(size_t)gi * D_ + ko * 8];
        int byt = (il << 8) + (ko << 4); byt ^= (il & 7) << 4;
        *(uint4*)(Bt + byt) = v;
    }
    const unsigned short* wsp = WsT + (size_t)l * D_ * D_;
#pragma unroll
    for (int p = 0; p < 4; ++p) {
        int o = tid + p * 512;
        int dout = o >> 4, ko = o & 15;
        uint4 v = *(const uint4*)&wsp[dout * 128 + ko * 8];
        int byt = (dout << 8) + (ko << 4); byt ^= (dout & 7) << 4;
        *(uint4*)(At + byt) = v;
    }
    __syncthreads();
    gemm128();

    // ---- epilogue: bias + silu -> LDS tiles -> coalesced uint4 stores ----
    __syncthreads();   // all phase-2 LDS reads done before overwrite
    const float* blp = bL + (size_t)l * D_;
#pragma unroll
    for (int fr = 0; fr < 4; ++fr)
#pragma unroll
        for (int fc = 0; fc < 2; ++fc) {
            int dbase = wrow * 64 + fr * 16 + ((lane >> 4) << 2);
            int ib = wcol * 32 + fc * 16 + (lane & 15);
            int gi = i0 + ib;
            f32x4 v = acc[fr][fc];
            float4 bias = *(const float4*)&blp[dbase];
            float o0 = silu_f(v[0] + bias.x);
            float o1 = silu_f(v[1] + bias.y);
            float o2 = silu_f(v[2] + bias.z);
            float o3 = silu_f(v[3] + bias.w);
            if (gi >= N_) { o0 = 0.f; o1 = 0.f; o2 = 0.f; o3 = 0.f; }
            unsigned short b0 = f2bf(o0), b1 = f2bf(o1);
            unsigned short b2 = f2bf(o2), b3 = f2bf(o3);
            char* pI = tileI + ib * 272 + dbase * 2;
            *(uint32_t*)pI       = (uint32_t)b0 | ((uint32_t)b1 << 16);
            *(uint32_t*)(pI + 4) = (uint32_t)b2 | ((uint32_t)b3 << 16);
            *(unsigned short*)(tileT + (dbase    ) * 272 + ib * 2) = b0;
            *(unsigned short*)(tileT + (dbase + 1) * 272 + ib * 2) = b1;
            *(unsigned short*)(tileT + (dbase + 2) * 272 + ib * 2) = b2;
            *(unsigned short*)(tileT + (dbase + 3) * 272 + ib * 2) = b3;
        }
    __syncthreads();
    unsigned short* hgO  = hout  + (size_t)g * NP_ * D_;
    unsigned short* hgOT = houtT + (size_t)g * D_ * NP_;
#pragma unroll
    for (int p = 0; p < 4; ++p) {
        int o = tid + p * 512;        // 0..2047
        int r = o >> 4, seg = o & 15;
        uint4 vI = *(const uint4*)(tileI + r * 272 + seg * 16);
        *(uint4*)&hgO[(size_t)(i0 + r) * D_ + seg * 8] = vI;
        uint4 vT = *(const uint4*)(tileT + r * 272 + seg * 16);
        *(uint4*)&hgOT[(size_t)r * NP_ + i0 + seg * 8] = vT;
    }
}

// ---------------------------------------------------------------------------
// K4: global mean pool + output projection (f32 accumulation from bf16 h)
// ---------------------------------------------------------------------------
__global__ __launch_bounds__(256) void pool_kernel(const unsigned short* __restrict__ h,
                                                   const float* __restrict__ Wo,
                                                   float* __restrict__ out) {
    int g = blockIdx.x, tid = threadIdx.x;
    const unsigned short* hg = h + (size_t)g * NP_ * D_;
    float a8[8];
#pragma unroll
    for (int e = 0; e < 8; ++e) a8[e] = 0.f;
    int d0 = (tid & 15) * 8;
    for (int i = tid >> 4; i < N_; i += 16) {
        uint4 v = *(const uint4*)&hg[(size_t)i * D_ + d0];
        const unsigned short* pu = (const unsigned short*)&v;
#pragma unroll
        for (int e = 0; e < 8; ++e) a8[e] += bf2f(pu[e]);
    }
    __shared__ float red[16][D_];
#pragma unroll
    for (int e = 0; e < 8; ++e) red[tid >> 4][d0 + e] = a8[e];
    __syncthreads();
    __shared__ float pooled[D_];
    if (tid < D_) {
        float s = 0.f;
#pragma unroll
        for (int grp = 0; grp < 16; ++grp) s += red[grp][tid];
        pooled[tid] = s * (1.0f / (float)N_);
    }
    __syncthreads();
    if (tid < D_) {
        float accv = 0.f;
        for (int k = 0; k < D_; ++k) accv += pooled[k] * Wo[(size_t)k * D_ + tid];
        out[(size_t)g * D_ + tid] = accv;
    }
}

// ---------------------------------------------------------------------------
extern "C" void kernel_launch(void* const* d_in, const int* in_sizes, int n_in,
                              void* d_out, int out_size, void* d_ws, size_t ws_size,
                              hipStream_t stream) {
    (void)in_sizes; (void)n_in; (void)out_size; (void)ws_size;
    const float* x  = (const float*)d_in[0];
    const float* Wn = (const float*)d_in[1];
    const float* bn = (const float*)d_in[2];
    const float* Ws = (const float*)d_in[3];
    const float* Wm = (const float*)d_in[4];
    const float* bL = (const float*)d_in[5];
    const float* we = (const float*)d_in[6];
    const float* be = (const float*)d_in[7];
    const float* Wo = (const float*)d_in[8];
    float* out = (float*)d_out;

    char* w = (char*)d_ws;
    uint32_t*       adj  = (uint32_t*)w;        w += ADJ_BYTES;
    uint32_t*       ebuf = (uint32_t*)w;        w += EBUF_BYTES;
    uint32_t*       ecnt = (uint32_t*)w;        w += ECNT_BYTES;
    unsigned short* hA   = (unsigned short*)w;  w += HB_BYTES;
    unsigned short* hAT  = (unsigned short*)w;  w += HB_BYTES;
    unsigned short* hB   = (unsigned short*)w;  w += HB_BYTES;
    unsigned short* hBT  = (unsigned short*)w;  w += HB_BYTES;
    unsigned short* WsT  = (unsigned short*)w;  w += WT_BYTES;
    unsigned short* WmT  = (unsigned short*)w;  w += WT_BYTES;

    hipFuncSetAttribute((const void*)layer_kernel,
                        hipFuncAttributeMaxDynamicSharedMemorySize, LDS_TOTAL);

    knn_kernel<<<G_ * ROWT, 256, 0, stream>>>(x, adj);
    ebuild_kernel<<<G_, 512, 0, stream>>>(x, adj, ebuf, ecnt);
    wprep_kernel<<<(2 * L_ * D_ * D_) / 256, 256, 0, stream>>>(Ws, Wm, WsT, WmT);
    enc_kernel<<<G_, 256, 0, stream>>>(x, Wn, bn, hA, hAT);

    for (int l = 0; l < L_; ++l) {
        const unsigned short* hi  = (l & 1) ? hB  : hA;
        const unsigned short* hiT = (l & 1) ? hBT : hAT;
        unsigned short* ho  = (l & 1) ? hA  : hB;
        unsigned short* hoT = (l & 1) ? hAT : hBT;
        layer_kernel<<<G_ * 4, 512, LDS_TOTAL, stream>>>(ebuf, ecnt, hi, hiT, ho, hoT,
                                                         WsT, WmT, bL, we, be, l);
    }

    pool_kernel<<<G_, 256, 0, stream>>>(hA, Wo, out);
}